// Round 8
// baseline (553.087 us; speedup 1.0000x reference)
//
#include <hip/hip_runtime.h>

namespace {
constexpr int MD  = 4;
constexpr int BB  = 8, CCH = 128, HH = 96, WW = 192;
constexpr int TH  = 16, TW = 48, WPT = 12;   // tile 16 x 48, 12 px/thread
constexpr int NJ  = 15;        // f4 per staged row (60 floats: w0-4 .. w0+55)
constexpr int ROWS = 16;       // staged rows (h0+r .. h0+r+15)
constexpr int F4B  = 256;      // buffer f4 (240 used + 16 junk), 4096 B
constexpr int NBUF = 4;        // quad buffer, 2 chunks in flight
constexpr int NCH  = CCH;      // 128 chunks (1 channel each)
}

__device__ __forceinline__ void gload16(const float* g, float* l) {
    __builtin_amdgcn_global_load_lds(
        (const __attribute__((address_space(1))) void*)g,
        (__attribute__((address_space(3))) void*)l, 16, 0, 0);
}

__global__ __launch_bounds__(64, 2)
void corr81(const float* __restrict__ in0,
            const float* __restrict__ in1,
            const float* __restrict__ zp,    // >=16B zero page (d_ws)
            float* __restrict__ out)
{
    const int lane = threadIdx.x;          // one wave per block
    const int g = lane >> 2;               // h-row in tile (0..15)
    const int q = lane & 3;                // w-group: owns w0+q*12 .. +11

    const int rr = blockIdx.x % 9, wt = blockIdx.x / 9;
    const int ht = blockIdx.y,     b  = blockIdx.z;
    const int w0 = wt * TW, h0 = ht * TH;
    const int r  = rr - MD;                // displacement row offset

    __shared__ float lds[NBUF * F4B * 4];  // 16 KB, wave-private

    const size_t plane = (size_t)HH * WW;
    const size_t img   = (size_t)CCH * plane;
    const float* in1b  = in1 + (size_t)b * img;

    // in1 staging: DMA i lands at slot i*64+lane (wave-uniform base + lane*16).
    // slot s -> (row s/15, granule s%15); row stride 15 f4 (odd) -> uniform
    // bank-residue spread on the b128 window reads, no swizzle needed.
    const float* gsrc[NBUF == 4 ? 4 : 4];
    #pragma unroll
    for (int i = 0; i < 4; ++i) {
        const int s   = i * 64 + lane;
        const int row = s / NJ, j = s % NJ;
        const int hr  = h0 + r + row;
        const int wc  = w0 - 4 + 4 * j;
        const bool ok = (s < ROWS * NJ) && hr >= 0 && hr < HH
                        && wc >= 0 && wc <= WW - 4;
        gsrc[i] = ok ? (in1b + (size_t)hr * WW + wc) : zp;
    }

    const float* pin0 = in0 + (size_t)b * img
                      + (size_t)(h0 + g) * WW + (w0 + q * WPT);

    float acc[9][WPT];
    #pragma unroll
    for (int cc = 0; cc < 9; ++cc)
        #pragma unroll
        for (int j = 0; j < WPT; ++j) acc[cc][j] = 0.f;

    auto issueTo = [&](int u, int bufidx, float4& x0, float4& x1, float4& x2) {
        float* bf = &lds[bufidx * F4B * 4];
        const size_t coff = (size_t)u * plane;
        #pragma unroll
        for (int i = 0; i < 4; ++i) {
            const float* gp = gsrc[i];
            gload16(gp == zp ? gp : gp + coff, bf + (size_t)(i * 64 + lane) * 4);
        }
        const float* p = pin0 + coff;
        x0 = *(const float4*)(p + 0);
        x1 = *(const float4*)(p + 4);
        x2 = *(const float4*)(p + 8);
    };

    auto compute = [&](int bufidx, const float4& x0, const float4& x1,
                       const float4& x2) {
        const float* bf = &lds[bufidx * F4B * 4];
        const float av[WPT] = {x0.x, x0.y, x0.z, x0.w,
                               x1.x, x1.y, x1.z, x1.w,
                               x2.x, x2.y, x2.z, x2.w};
        const float4* rbase = (const float4*)bf + (g * NJ + 3 * q);
        float wn[20];
        #pragma unroll
        for (int k = 0; k < 5; ++k) {
            const float4 w4 = rbase[k];
            wn[4*k+0] = w4.x; wn[4*k+1] = w4.y;
            wn[4*k+2] = w4.z; wn[4*k+3] = w4.w;
        }
        #pragma unroll
        for (int cc = 0; cc < 9; ++cc)
            #pragma unroll
            for (int j = 0; j < WPT; ++j)
                acc[cc][j] = fmaf(av[j], wn[cc + j], acc[cc][j]);
    };

    float4 rA0, rA1, rA2, rB0, rB1, rB2;

    // prologue: 2 chunks in flight
    issueTo(0, 0, rA0, rA1, rA2);
    issueTo(1, 1, rB0, rB1, rB2);

    int cur = 0;
    for (int t = 0; t < NCH - 2; t += 2) {
        __builtin_amdgcn_sched_barrier(0);
        asm volatile("s_waitcnt vmcnt(7)" ::: "memory");   // chunk t landed
        __builtin_amdgcn_sched_barrier(0);
        compute(cur, rA0, rA1, rA2);
        __builtin_amdgcn_sched_barrier(0);
        issueTo(t + 2, (cur + 2) & 3, rA0, rA1, rA2);

        __builtin_amdgcn_sched_barrier(0);
        asm volatile("s_waitcnt vmcnt(7)" ::: "memory");   // chunk t+1 landed
        __builtin_amdgcn_sched_barrier(0);
        compute((cur + 1) & 3, rB0, rB1, rB2);
        __builtin_amdgcn_sched_barrier(0);
        issueTo(t + 3, (cur + 3) & 3, rB0, rB1, rB2);
        cur = (cur + 2) & 3;
    }
    // tail: chunks 126,127 already issued
    __builtin_amdgcn_sched_barrier(0);
    asm volatile("s_waitcnt vmcnt(3)" ::: "memory");       // chunk 126 landed
    __builtin_amdgcn_sched_barrier(0);
    compute(cur, rA0, rA1, rA2);
    __builtin_amdgcn_sched_barrier(0);
    asm volatile("s_waitcnt vmcnt(0)" ::: "memory");       // chunk 127 landed
    __builtin_amdgcn_sched_barrier(0);
    compute((cur + 1) & 3, rB0, rB1, rB2);

    // epilogue: plain coalesced stores
    const float scale = 1.0f / CCH;
    float* ob = out + ((size_t)b * 81 + (size_t)rr * 9) * plane
                    + (size_t)(h0 + g) * WW + (w0 + q * WPT);
    #pragma unroll
    for (int cc = 0; cc < 9; ++cc) {
        float* oc = ob + (size_t)cc * plane;
        #pragma unroll
        for (int k = 0; k < 3; ++k) {
            float4 o = make_float4(acc[cc][4*k+0] * scale, acc[cc][4*k+1] * scale,
                                   acc[cc][4*k+2] * scale, acc[cc][4*k+3] * scale);
            *(float4*)(oc + 4 * k) = o;
        }
    }
}

extern "C" void kernel_launch(void* const* d_in, const int* in_sizes, int n_in,
                              void* d_out, int out_size, void* d_ws, size_t ws_size,
                              hipStream_t stream)
{
    const float* in0 = (const float*)d_in[0];
    const float* in1 = (const float*)d_in[1];
    float* out = (float*)d_out;
    hipMemsetAsync(d_ws, 0, 256, stream);            // zero page for OOB staging
    dim3 grid(9 * (WW / TW), HH / TH, BB);           // 36 x 6 x 8 = 1728 blocks
    corr81<<<grid, dim3(64), 0, stream>>>(in0, in1, (const float*)d_ws, out);
}